// Round 9
// baseline (206.107 us; speedup 1.0000x reference)
//
#include <hip/hip_runtime.h>
#include <hip/hip_bf16.h>

#define BATCH 8192
#define IDIM 256
#define ODIM 256

#define NC 8
#define IPC 32            // i-values per K-chunk
#define THREADS 256
#define RG_TOT 4096       // (2*IDIM*KGRID)/8

typedef __attribute__((ext_vector_type(8))) short short8;
typedef __attribute__((ext_vector_type(4))) float float4v;
typedef __attribute__((ext_vector_type(16))) float float16v;
typedef __attribute__((ext_vector_type(4))) unsigned int uint4v;

#define INV2PI 0.15915494309189535f

// pack two f32 -> (bf16(c) | bf16(s)<<16), RTNE
__device__ __forceinline__ unsigned int bf16pack(float c, float s) {
    union { float f; unsigned int u; } a, b;
    a.f = c; b.f = s;
    unsigned int ua = a.u + (0x7fffu + ((a.u >> 16) & 1u));
    unsigned int ub = b.u + (0x7fffu + ((b.u >> 16) & 1u));
    return (ua >> 16) | (ub & 0xffff0000u);
}

__device__ __forceinline__ unsigned int cvtpk(float c, float s) {
    union { __hip_bfloat162 h2; unsigned int w; } cv;
    cv.h2 = __float22bfloat162_rn(make_float2(c, s));
    return cv.w;
}

// W[2][256][256][64] f32  ->  Bw[rg=4096][j=256][8] bf16, read-coalesced
__global__ void prep_w(const float4v* __restrict__ W, uint4v* __restrict__ Bw) {
    int tid = blockIdx.x * 256 + threadIdx.x;   // 1,048,576 threads
    int rg = tid & 4095;
    int j = tid >> 12;
    float4v c4 = W[j * 4096 + rg];
    float4v s4 = W[1048576 + j * 4096 + rg];
    uint4v o;
    o.x = bf16pack(c4.x, s4.x);
    o.y = bf16pack(c4.y, s4.y);
    o.z = bf16pack(c4.z, s4.z);
    o.w = bf16pack(c4.w, s4.w);
    Bw[rg * 256 + j] = o;
}

// 4 waves/block, wave tile 64 rows x 64 cols via 32x32x16 MFMA.
// A-fragments built fully IN REGISTERS (lane computes cos/sin for its own
// row at multipliers 8ks+4g+{1..4}); B kept in register dbuf from global.
// No LDS, no __syncthreads -> no block-wide phase-lock; waves on a SIMD
// come from different blocks and overlap VALU with MFMA freely.
__global__ __launch_bounds__(THREADS, 3) void kan_main(
    const float* __restrict__ x,
    const short* __restrict__ Bw,
    float* __restrict__ part)
{
    const int bx = blockIdx.x;
    const int chunk = bx & 7;          // K-chunk == XCD id (1024 blocks)
    const int wn = (bx >> 3) & 3;      // 64-col quarter (shared by block)
    const int mb = bx >> 5;            // M-block 0..31 (256 rows)
    const int b0 = mb * 256;
    const int i0 = chunk * IPC;
    const int t = threadIdx.x;
    const int lane = t & 63;
    const int wave = t >> 6;           // 0..3 -> 64-row slice
    const int g = lane >> 5;           // k-octet half

    const int row0 = b0 + wave * 64 + (lane & 31);
    const float* xp0 = x + (size_t)row0 * IDIM + i0;
    const float* xp1 = xp0 + (size_t)32 * IDIM;

    // B slot = rg*256 + col; rg = chunk*512 + gq*2 + g;
    // col = wn*64 + f*32 + (lane&31)   (layout verified R4/R7/R8)
    const short8* Bp = (const short8*)Bw
        + (size_t)(chunk * 512 + g) * 256 + wn * 64 + (lane & 31);

    short8 bB[2][2];
    bB[0][0] = Bp[0];       bB[0][1] = Bp[32];        // gq = 0
    bB[1][0] = Bp[512];     bB[1][1] = Bp[512 + 32];  // gq = 1

    float16v acc[2][2];
    acc[0][0] = (float16v)(0.0f);
    acc[0][1] = (float16v)(0.0f);
    acc[1][0] = (float16v)(0.0f);
    acc[1][1] = (float16v)(0.0f);

    float xv0 = xp0[0];
    float xv1 = xp1[0];

    const float mbase = (float)(4 * g + 1);

    for (int p = 0; p < IPC; ++p) {
        // prefetch next i's x (L1-resident after first touch)
        const int pn = (p + 1 < IPC) ? (p + 1) : p;
        float xn0 = xp0[pn];
        float xn1 = xp1[pn];

        const float xk0 = xv0 * INV2PI;
        const float xk1 = xv1 * INV2PI;

        // init 4 (cos,sin) pairs per rowset at multipliers 4g+{1..4}
        float c0[4], s0[4], c1[4], s1[4];
        #pragma unroll
        for (int u = 0; u < 4; ++u) {
            float r0 = xk0 * (mbase + (float)u); r0 -= floorf(r0);
            c0[u] = __builtin_amdgcn_cosf(r0);
            s0[u] = __builtin_amdgcn_sinf(r0);
            float r1 = xk1 * (mbase + (float)u); r1 -= floorf(r1);
            c1[u] = __builtin_amdgcn_cosf(r1);
            s1[u] = __builtin_amdgcn_sinf(r1);
        }
        // step rotation: +8 multipliers
        float t0 = 8.0f * xk0; t0 -= floorf(t0);
        const float c80 = __builtin_amdgcn_cosf(t0);
        const float s80 = __builtin_amdgcn_sinf(t0);
        float t1 = 8.0f * xk1; t1 -= floorf(t1);
        const float c81 = __builtin_amdgcn_cosf(t1);
        const float s81 = __builtin_amdgcn_sinf(t1);

        #pragma unroll
        for (int ks = 0; ks < 8; ++ks) {
            // pack A-fragments for this k-step
            uint4v w0, w1;
            #pragma unroll
            for (int u = 0; u < 4; ++u) {
                w0[u] = cvtpk(c0[u], s0[u]);
                w1[u] = cvtpk(c1[u], s1[u]);
            }
            short8 a0 = __builtin_bit_cast(short8, w0);
            short8 a1 = __builtin_bit_cast(short8, w1);
            acc[0][0] = __builtin_amdgcn_mfma_f32_32x32x16_bf16(a0, bB[ks & 1][0], acc[0][0], 0, 0, 0);
            acc[1][0] = __builtin_amdgcn_mfma_f32_32x32x16_bf16(a1, bB[ks & 1][0], acc[1][0], 0, 0, 0);
            acc[0][1] = __builtin_amdgcn_mfma_f32_32x32x16_bf16(a0, bB[ks & 1][1], acc[0][1], 0, 0, 0);
            acc[1][1] = __builtin_amdgcn_mfma_f32_32x32x16_bf16(a1, bB[ks & 1][1], acc[1][1], 0, 0, 0);
            // prefetch B for k-step gq = p*8+ks+2 into the slot just freed
            int gq = p * 8 + ks + 2;
            if (gq > 255) gq = 255;               // tail clamp, data unused
            bB[ks & 1][0] = Bp[(size_t)gq * 512];
            bB[ks & 1][1] = Bp[(size_t)gq * 512 + 32];
            // advance pairs by +8 multipliers
            if (ks < 7) {
                #pragma unroll
                for (int u = 0; u < 4; ++u) {
                    float cn = c0[u] * c80 - s0[u] * s80;
                    float sn = s0[u] * c80 + c0[u] * s80;
                    c0[u] = cn; s0[u] = sn;
                    cn = c1[u] * c81 - s1[u] * s81;
                    sn = s1[u] * c81 + c1[u] * s81;
                    c1[u] = cn; s1[u] = sn;
                }
            }
        }
        xv0 = xn0; xv1 = xn1;
        // rendezvous only (no waitcnt drain): keeps the block's 4 waves
        // aligned so their shared 64-col B slice stays hot in L1
        __builtin_amdgcn_s_barrier();
    }

    // ---- store partials: part[chunk][b][j] ----
    // 32x32 C/D (verified R4/R7/R8): col = lane&31,
    // row = (v&3) + 8*(v>>2) + 4*(lane>>5)
    const int cb = wn * 64 + (lane & 31);
    const int rb = b0 + wave * 64 + 4 * (lane >> 5);
    float* pc = part + (size_t)chunk * (BATCH * ODIM);
    #pragma unroll
    for (int rt = 0; rt < 2; ++rt)
        #pragma unroll
        for (int f = 0; f < 2; ++f)
            #pragma unroll
            for (int v = 0; v < 16; ++v) {
                int r = rb + rt * 32 + (v & 3) + 8 * (v >> 2);
                pc[(size_t)r * ODIM + cb + f * 32] = acc[rt][f][v];
            }
}

__global__ void reduce_bias(const float4v* __restrict__ part,
                            const float4v* __restrict__ bias,
                            float4v* __restrict__ out)
{
    const int tid = blockIdx.x * 256 + threadIdx.x;   // 524288 float4s
    const int Q = BATCH * ODIM / 4;
    float4v r = part[tid];
    #pragma unroll
    for (int c = 1; c < NC; ++c) r += part[tid + c * Q];
    r += bias[tid & 63];
    out[tid] = r;
}

extern "C" void kernel_launch(void* const* d_in, const int* in_sizes, int n_in,
                              void* d_out, int out_size, void* d_ws, size_t ws_size,
                              hipStream_t stream)
{
    const float* x = (const float*)d_in[0];
    const float* W = (const float*)d_in[1];
    const float* bias = (const float*)d_in[2];
    float* out = (float*)d_out;

    const size_t bw_bytes = (size_t)RG_TOT * 256 * 16;   // 16.78 MB

    short* Bw = (short*)d_ws;
    float* part = (float*)((char*)d_ws + bw_bytes);      // 67.1 MB (ws>=84MB proven R3)

    prep_w<<<4096, 256, 0, stream>>>((const float4v*)W, (uint4v*)Bw);
    // 1024 blocks x 256 thr; no LDS; <=170 regs -> 12 waves/CU
    kan_main<<<(BATCH / 256) * 4 * NC, THREADS, 0, stream>>>(x, Bw, part);
    reduce_bias<<<(BATCH * ODIM / 4) / 256, 256, 0, stream>>>(
        (const float4v*)part, (const float4v*)bias, (float4v*)out);
}

// Round 10
// 182.312 us; speedup vs baseline: 1.1305x; 1.1305x over previous
//
#include <hip/hip_runtime.h>
#include <hip/hip_bf16.h>

#define BATCH 8192
#define IDIM 256
#define ODIM 256

#define NC 4
#define IPC 64            // i-values per K-chunk
#define THREADS 256
#define RG_TOT 4096       // (2*IDIM*KGRID)/8

typedef __attribute__((ext_vector_type(8))) short short8;
typedef __attribute__((ext_vector_type(4))) float float4v;
typedef __attribute__((ext_vector_type(16))) float float16v;
typedef __attribute__((ext_vector_type(4))) unsigned int uint4v;

#define INV2PI 0.15915494309189535f

// pack two f32 -> (bf16(c) | bf16(s)<<16), RTNE (prep_w only)
__device__ __forceinline__ unsigned int bf16pack(float c, float s) {
    union { float f; unsigned int u; } a, b;
    a.f = c; b.f = s;
    unsigned int ua = a.u + (0x7fffu + ((a.u >> 16) & 1u));
    unsigned int ub = b.u + (0x7fffu + ((b.u >> 16) & 1u));
    return (ua >> 16) | (ub & 0xffff0000u);
}

// single-instruction pack: lo = bf16(c), hi = bf16(s)  (T12: no builtin on gfx950)
__device__ __forceinline__ unsigned int cvtpk(float c, float s) {
    unsigned int r;
    asm("v_cvt_pk_bf16_f32 %0, %1, %2" : "=v"(r) : "v"(c), "v"(s));
    return r;
}

// W[2][256][256][64] f32  ->  Bw[rg=4096][j=256][8] bf16, read-coalesced
__global__ void prep_w(const float4v* __restrict__ W, uint4v* __restrict__ Bw) {
    int tid = blockIdx.x * 256 + threadIdx.x;   // 1,048,576 threads
    int rg = tid & 4095;
    int j = tid >> 12;
    float4v c4 = W[j * 4096 + rg];
    float4v s4 = W[1048576 + j * 4096 + rg];
    uint4v o;
    o.x = bf16pack(c4.x, s4.x);
    o.y = bf16pack(c4.y, s4.y);
    o.z = bf16pack(c4.z, s4.z);
    o.w = bf16pack(c4.w, s4.w);
    Bw[rg * 256 + j] = o;
}

// 4 waves/block, wave tile 32 rows x 128 cols via 32x32x16 MFMA.
// A-fragments built in registers (lane computes cos/sin of its own row at
// multipliers 8ks+4g+{1..4}); B register-dbuf from global (L1/L2-resident).
// No LDS, no __syncthreads -> no phase-lock. Feature redundancy 2x (wn halves).
__global__ __launch_bounds__(THREADS, 3) void kan_main(
    const float* __restrict__ x,
    const short8* __restrict__ Bw,
    float* __restrict__ part)
{
    const int bx = blockIdx.x;
    const int chunk = bx & 3;          // K-chunk
    const int wn = (bx >> 2) & 1;      // 128-col half; (chunk,wn) == XCD id
    const int mb = bx >> 3;            // M-block 0..63 (128 rows)
    const int b0 = mb * 128;
    const int i0 = chunk * IPC;
    const int t = threadIdx.x;
    const int lane = t & 63;
    const int wave = t >> 6;           // 0..3 -> 32-row slice
    const int g = lane >> 5;           // k-octet half

    const int row = b0 + wave * 32 + (lane & 31);
    const float* xp = x + (size_t)row * IDIM + i0;

    // B slot = rg*256 + col; rg = chunk*1024 + gq*2 + g;
    // col = wn*128 + f*32 + (lane&31)   (layout verified R4..R9)
    const short8* Bp = Bw + (size_t)(chunk * 1024 + g) * 256
                          + wn * 128 + (lane & 31);

    short8 bB[2][4];
    #pragma unroll
    for (int f = 0; f < 4; ++f) bB[0][f] = Bp[f * 32];          // gq = 0
    const short8* Bq = Bp + 512;                                 // gq = 1
    #pragma unroll
    for (int f = 0; f < 4; ++f) bB[1][f] = Bq[f * 32];
    Bq += 512;                                                   // gq = 2

    float16v acc[4];
    #pragma unroll
    for (int f = 0; f < 4; ++f) acc[f] = (float16v)(0.0f);

    float xv = xp[0];
    const float mbase = (float)(4 * g + 1);

    for (int p = 0; p < IPC; ++p) {
        float xn = xp[(p + 1 < IPC) ? (p + 1) : p];
        const float xk = xv * INV2PI;

        // init 4 (cos,sin) pairs at multipliers 4g+{1..4}
        float c0[4], s0[4];
        #pragma unroll
        for (int u = 0; u < 4; ++u) {
            float r0 = __builtin_amdgcn_fractf(xk * (mbase + (float)u));
            c0[u] = __builtin_amdgcn_cosf(r0);
            s0[u] = __builtin_amdgcn_sinf(r0);
        }
        // +8-multiplier rotation constants
        float t8 = __builtin_amdgcn_fractf(8.0f * xk);
        const float c8 = __builtin_amdgcn_cosf(t8);
        const float s8 = __builtin_amdgcn_sinf(t8);

        #pragma unroll
        for (int ks = 0; ks < 8; ++ks) {
            uint4v w;
            #pragma unroll
            for (int u = 0; u < 4; ++u) w[u] = cvtpk(c0[u], s0[u]);
            short8 a = __builtin_bit_cast(short8, w);
            #pragma unroll
            for (int f = 0; f < 4; ++f)
                acc[f] = __builtin_amdgcn_mfma_f32_32x32x16_bf16(
                    a, bB[ks & 1][f], acc[f], 0, 0, 0);
            // prefetch gq = p*8+ks+2 into the slot just freed; final iters
            // run <=12KB past the chunk (lands in part buffer, never consumed)
            #pragma unroll
            for (int f = 0; f < 4; ++f) bB[ks & 1][f] = Bq[f * 32];
            Bq += 512;
            if (ks < 7) {
                #pragma unroll
                for (int u = 0; u < 4; ++u) {
                    float cn = fmaf(-s0[u], s8, c0[u] * c8);
                    float sn = fmaf( c0[u], s8, s0[u] * c8);
                    c0[u] = cn; s0[u] = sn;
                }
            }
        }
        xv = xn;
        // rendezvous (no waitcnt drain): keeps the 4 waves' shared B hot in L1
        __builtin_amdgcn_s_barrier();
    }

    // ---- store partials: part[chunk][b][j] ----
    // 32x32 C/D (verified R4..R9): col = lane&31,
    // row = (v&3) + 8*(v>>2) + 4*(lane>>5)
    const int cb = wn * 128 + (lane & 31);
    const int rb = b0 + wave * 32 + 4 * g;
    float* pc = part + (size_t)chunk * (BATCH * ODIM);
    #pragma unroll
    for (int f = 0; f < 4; ++f)
        #pragma unroll
        for (int v = 0; v < 16; ++v) {
            int r = rb + (v & 3) + 8 * (v >> 2);
            pc[(size_t)r * ODIM + cb + f * 32] = acc[f][v];
        }
}

__global__ void reduce_bias(const float4v* __restrict__ part,
                            const float4v* __restrict__ bias,
                            float4v* __restrict__ out)
{
    const int tid = blockIdx.x * 256 + threadIdx.x;   // 524288 float4s
    const int Q = BATCH * ODIM / 4;
    float4v r = part[tid];
    #pragma unroll
    for (int c = 1; c < NC; ++c) r += part[tid + c * Q];
    r += bias[tid & 63];
    out[tid] = r;
}

extern "C" void kernel_launch(void* const* d_in, const int* in_sizes, int n_in,
                              void* d_out, int out_size, void* d_ws, size_t ws_size,
                              hipStream_t stream)
{
    const float* x = (const float*)d_in[0];
    const float* W = (const float*)d_in[1];
    const float* bias = (const float*)d_in[2];
    float* out = (float*)d_out;

    const size_t bw_bytes = (size_t)RG_TOT * 256 * 16;   // 16.78 MB

    short8* Bw = (short8*)d_ws;
    float* part = (float*)((char*)d_ws + bw_bytes);      // 33.5 MB (NC=4)

    prep_w<<<4096, 256, 0, stream>>>((const float4v*)W, (uint4v*)Bw);
    // 512 blocks x 256 thr; no LDS; ~132 regs (cap 170) -> 2 blocks/CU resident
    kan_main<<<(BATCH / 128) * 2 * NC, THREADS, 0, stream>>>(x, Bw, part);
    reduce_bias<<<(BATCH * ODIM / 4) / 256, 256, 0, stream>>>(
        (const float4v*)part, (const float4v*)bias, (float4v*)out);
}

// Round 11
// 160.109 us; speedup vs baseline: 1.2873x; 1.1387x over previous
//
#include <hip/hip_runtime.h>
#include <hip/hip_bf16.h>

#define BATCH 8192
#define IDIM 256
#define ODIM 256

#define NC 8
#define IPC 32            // i-values per K-chunk
#define THREADS 256
#define RG_TOT 4096       // (2*IDIM*KGRID)/8

typedef __attribute__((ext_vector_type(8))) short short8;
typedef __attribute__((ext_vector_type(4))) float float4v;
typedef __attribute__((ext_vector_type(16))) float float16v;
typedef __attribute__((ext_vector_type(4))) unsigned int uint4v;

#define INV2PI 0.15915494309189535f

// pack two f32 -> (bf16(c) | bf16(s)<<16), RTNE (prep_w only)
__device__ __forceinline__ unsigned int bf16pack(float c, float s) {
    union { float f; unsigned int u; } a, b;
    a.f = c; b.f = s;
    unsigned int ua = a.u + (0x7fffu + ((a.u >> 16) & 1u));
    unsigned int ub = b.u + (0x7fffu + ((b.u >> 16) & 1u));
    return (ua >> 16) | (ub & 0xffff0000u);
}

// single-instruction pack: lo = bf16(c), hi = bf16(s)
__device__ __forceinline__ unsigned int cvtpk(float c, float s) {
    unsigned int r;
    asm("v_cvt_pk_bf16_f32 %0, %1, %2" : "=v"(r) : "v"(c), "v"(s));
    return r;
}

// W[2][256][256][64] f32  ->  Bw[rg=4096][j=256][8] bf16, read-coalesced
__global__ void prep_w(const float4v* __restrict__ W, uint4v* __restrict__ Bw) {
    int tid = blockIdx.x * 256 + threadIdx.x;   // 1,048,576 threads
    int rg = tid & 4095;
    int j = tid >> 12;
    float4v c4 = W[j * 4096 + rg];
    float4v s4 = W[1048576 + j * 4096 + rg];
    uint4v o;
    o.x = bf16pack(c4.x, s4.x);
    o.y = bf16pack(c4.y, s4.y);
    o.z = bf16pack(c4.z, s4.z);
    o.w = bf16pack(c4.w, s4.w);
    Bw[rg * 256 + j] = o;
}

// 4 waves/block, wave tile 64 rows x 128 cols via 32x32x16 MFMA:
// 8 MFMA per 4 B-loads (2x the MFMA:L1 ratio of R10 -- L1 path was the
// hidden 60%-busy pipe). A-fragments in registers (2 rowsets), B register-
// dbuf from global (L1/L2-resident; all 8 waves/CU share addresses).
__global__ __launch_bounds__(THREADS, 2) void kan_main(
    const float* __restrict__ x,
    const short8* __restrict__ Bw,
    float* __restrict__ part)
{
    const int bx = blockIdx.x;
    const int chunk = bx & 7;          // K-chunk == XCD id (512 blocks)
    const int wn = (bx >> 3) & 1;      // 128-col half
    const int mb = bx >> 4;            // M-block 0..31 (256 rows)
    const int b0 = mb * 256;
    const int i0 = chunk * IPC;
    const int t = threadIdx.x;
    const int lane = t & 63;
    const int wave = t >> 6;           // 0..3 -> 64-row slice
    const int g = lane >> 5;           // k-octet half

    const int row0 = b0 + wave * 64 + (lane & 31);
    const float* xp0 = x + (size_t)row0 * IDIM + i0;
    const float* xp1 = xp0 + (size_t)32 * IDIM;   // rowset 1 (+32 rows)

    // B slot = rg*256 + col; rg = chunk*512 + gq*2 + g;
    // col = wn*128 + f*32 + (lane&31)   (layout verified R4..R10)
    const short8* Bp = Bw + (size_t)(chunk * 512 + g) * 256
                          + wn * 128 + (lane & 31);

    short8 bB[2][4];
    #pragma unroll
    for (int f = 0; f < 4; ++f) bB[0][f] = Bp[f * 32];          // gq = 0
    const short8* Bq = Bp + 512;                                 // gq = 1
    #pragma unroll
    for (int f = 0; f < 4; ++f) bB[1][f] = Bq[f * 32];
    Bq += 512;                                                   // gq = 2

    float16v acc[2][4];
    #pragma unroll
    for (int r = 0; r < 2; ++r)
        #pragma unroll
        for (int f = 0; f < 4; ++f) acc[r][f] = (float16v)(0.0f);

    float xv0 = xp0[0];
    float xv1 = xp1[0];
    const float mbase = (float)(4 * g + 1);

    for (int p = 0; p < IPC; ++p) {
        const int pn = (p + 1 < IPC) ? (p + 1) : p;
        float xn0 = xp0[pn];
        float xn1 = xp1[pn];
        const float xk0 = xv0 * INV2PI;
        const float xk1 = xv1 * INV2PI;

        // init 4 (cos,sin) pairs per rowset at multipliers 4g+{1..4}
        float c0[4], s0[4], c1[4], s1[4];
        #pragma unroll
        for (int u = 0; u < 4; ++u) {
            float r0 = __builtin_amdgcn_fractf(xk0 * (mbase + (float)u));
            c0[u] = __builtin_amdgcn_cosf(r0);
            s0[u] = __builtin_amdgcn_sinf(r0);
            float r1 = __builtin_amdgcn_fractf(xk1 * (mbase + (float)u));
            c1[u] = __builtin_amdgcn_cosf(r1);
            s1[u] = __builtin_amdgcn_sinf(r1);
        }
        // +8-multiplier rotation constants
        float t0 = __builtin_amdgcn_fractf(8.0f * xk0);
        const float c80 = __builtin_amdgcn_cosf(t0);
        const float s80 = __builtin_amdgcn_sinf(t0);
        float t1 = __builtin_amdgcn_fractf(8.0f * xk1);
        const float c81 = __builtin_amdgcn_cosf(t1);
        const float s81 = __builtin_amdgcn_sinf(t1);

        #pragma unroll
        for (int ks = 0; ks < 8; ++ks) {
            uint4v w0, w1;
            #pragma unroll
            for (int u = 0; u < 4; ++u) {
                w0[u] = cvtpk(c0[u], s0[u]);
                w1[u] = cvtpk(c1[u], s1[u]);
            }
            short8 a0 = __builtin_bit_cast(short8, w0);
            short8 a1 = __builtin_bit_cast(short8, w1);
            #pragma unroll
            for (int f = 0; f < 4; ++f) {
                acc[0][f] = __builtin_amdgcn_mfma_f32_32x32x16_bf16(
                    a0, bB[ks & 1][f], acc[0][f], 0, 0, 0);
                acc[1][f] = __builtin_amdgcn_mfma_f32_32x32x16_bf16(
                    a1, bB[ks & 1][f], acc[1][f], 0, 0, 0);
            }
            // prefetch gq = p*8+ks+2 into the slot just freed; tail iters run
            // <=16KB past the chunk (lands in part buffer, loaded-not-consumed)
            #pragma unroll
            for (int f = 0; f < 4; ++f) bB[ks & 1][f] = Bq[f * 32];
            Bq += 512;
            if (ks < 7) {
                #pragma unroll
                for (int u = 0; u < 4; ++u) {
                    float cn = fmaf(-s0[u], s80, c0[u] * c80);
                    float sn = fmaf( c0[u], s80, s0[u] * c80);
                    c0[u] = cn; s0[u] = sn;
                    cn = fmaf(-s1[u], s81, c1[u] * c81);
                    sn = fmaf( c1[u], s81, s1[u] * c81);
                    c1[u] = cn; s1[u] = sn;
                }
            }
        }
        xv0 = xn0; xv1 = xn1;
        // rendezvous (no waitcnt drain): keeps the 4 waves' shared B hot in L1
        __builtin_amdgcn_s_barrier();
    }

    // ---- store partials: part[chunk][b][j] ----
    // 32x32 C/D (verified R4..R10): col = lane&31,
    // row = (v&3) + 8*(v>>2) + 4*(lane>>5)
    const int cb = wn * 128 + (lane & 31);
    float* pc = part + (size_t)chunk * (BATCH * ODIM);
    #pragma unroll
    for (int rt = 0; rt < 2; ++rt) {
        const int rb = b0 + wave * 64 + rt * 32 + 4 * g;
        #pragma unroll
        for (int f = 0; f < 4; ++f)
            #pragma unroll
            for (int v = 0; v < 16; ++v) {
                int r = rb + (v & 3) + 8 * (v >> 2);
                pc[(size_t)r * ODIM + cb + f * 32] = acc[rt][f][v];
            }
    }
}

__global__ void reduce_bias(const float4v* __restrict__ part,
                            const float4v* __restrict__ bias,
                            float4v* __restrict__ out)
{
    const int tid = blockIdx.x * 256 + threadIdx.x;   // 524288 float4s
    const int Q = BATCH * ODIM / 4;
    float4v r = part[tid];
    #pragma unroll
    for (int c = 1; c < NC; ++c) r += part[tid + c * Q];
    r += bias[tid & 63];
    out[tid] = r;
}

extern "C" void kernel_launch(void* const* d_in, const int* in_sizes, int n_in,
                              void* d_out, int out_size, void* d_ws, size_t ws_size,
                              hipStream_t stream)
{
    const float* x = (const float*)d_in[0];
    const float* W = (const float*)d_in[1];
    const float* bias = (const float*)d_in[2];
    float* out = (float*)d_out;

    const size_t bw_bytes = (size_t)RG_TOT * 256 * 16;   // 16.78 MB

    short8* Bw = (short8*)d_ws;
    float* part = (float*)((char*)d_ws + bw_bytes);      // 67.1 MB (ws>=84MB proven R3)

    prep_w<<<4096, 256, 0, stream>>>((const float4v*)W, (uint4v*)Bw);
    // 512 blocks x 256 thr; no LDS; ~228 unified regs -> 2 waves/SIMD
    kan_main<<<(BATCH / 256) * 2 * NC, THREADS, 0, stream>>>(x, Bw, part);
    reduce_bias<<<(BATCH * ODIM / 4) / 256, 256, 0, stream>>>(
        (const float4v*)part, (const float4v*)bias, (float4v*)out);
}